// Round 14
// baseline (979.808 us; speedup 1.0000x reference)
//
#include <hip/hip_runtime.h>
#include <hip/hip_bf16.h>

// OrbitalGenerator: 1024 independent [128x256] slices through a 4-layer MPNN.
// One block per orbital, 512 threads (8 waves), wave w owns rows w*16..w*16+16.
// R14 = R10 structure redesigned to fit the (512,4) 64-arch/64-AGPR register
// split so TWO blocks co-reside per CU (4 waves/SIMD):
//  - residual frw[32] (bf16-packed u32) pinned to AGPRs via asm "+a" constraint
//  - LN2 stats computed from the raw[8] fragments read for tanh (replaces
//    256 in-MSG shuffles + ln2s LDS + combine; adds barrier B5; mean is
//    lane-local so no meansel shuffle)
//  - b-operands streamed in pairs (8 regs) in GEMM1/GEMM2
// Peak arch live ~55-60. Spill canary: FETCH/WRITE (revert to R10 if >500MB).

#define O_TOT 1024

typedef __bf16 bf16x8 __attribute__((ext_vector_type(8)));
typedef float f32x4 __attribute__((ext_vector_type(4)));

static __device__ __forceinline__ unsigned short f2bf(float f) {
  __bf16 b = (__bf16)f;
  unsigned short u;
  __builtin_memcpy(&u, &b, 2);
  return u;
}
static __device__ __forceinline__ unsigned int packbf(float a, float b) {
  return (unsigned int)f2bf(a) | ((unsigned int)f2bf(b) << 16);
}
static __device__ __forceinline__ float lo16f(unsigned int u) {
  unsigned int x = u << 16;
  float f;
  __builtin_memcpy(&f, &x, 4);
  return f;
}
static __device__ __forceinline__ float hi16f(unsigned int u) {
  unsigned int x = u & 0xffff0000u;
  float f;
  __builtin_memcpy(&f, &x, 4);
  return f;
}
static __device__ __forceinline__ float ftanh(float x) {
  float e = __expf(2.f * x);
  return 1.f - 2.f * __builtin_amdgcn_rcpf(e + 1.f);
}

struct alignas(8) US4 { unsigned short a, b, c, d; };

// XOR swizzles with 2 row bits -> 16 distinct 16B slots per 16 consecutive rows.
static __device__ __forceinline__ int swzA(int row, int cb) {  // [128][512B]
  return row * 512 + (cb ^ ((row & 7) << 4) ^ (((row >> 3) & 1) << 5));
}
static __device__ __forceinline__ int swzV(int row, int cb) {  // [256][256B]
  return row * 256 + (cb ^ ((row & 7) << 4) ^ (((row >> 3) & 1) << 5));
}

// ---------------- setup kernels (identical to R10) ----------------

__global__ void k_orbmap(const int* __restrict__ charges, const int* __restrict__ n_up_p,
                         const int* __restrict__ n_down_p, int* __restrict__ orb_nuc,
                         int* __restrict__ orb_t) {
  __shared__ int off[129];
  __shared__ int prec[128];
  int tid = threadIdx.x;
  if (tid == 0) {
    int a = 0;
    for (int n = 0; n < 128; ++n) { off[n] = a; a += charges[n]; }
    off[128] = a;
  }
  if (tid < 128) prec[tid] = charges[tid] * (charges[tid] - 1) / 2;
  __syncthreads();
  int nu = *n_up_p, nd = *n_down_p;
  for (int o = tid; o < O_TOT; o += 256) {
    int e;
    if (o < nu) e = o;
    else if (o < 512) e = o + nd;
    else if (o < 512 + nd) e = o + nu - 512;
    else e = o;
    int nn = -1, tt = 0;
    for (int n = 0; n < 128; ++n) {
      if (e >= off[n] && e < off[n + 1]) { nn = n; tt = prec[n] + (e - off[n]); }
    }
    orb_nuc[o] = nn;
    orb_t[o] = tt;
  }
}

// ewbf fragment-major: [l][h][mt(8)][k0(4)][lane(64)][j(8)] bf16 (1MB total).
__global__ void k_ew(const float* __restrict__ coords, const float* __restrict__ W_edge,
                     unsigned short* __restrict__ ewbf) {
  int i = blockIdx.x, j = threadIdx.x;
  float dx = coords[i * 3 + 0] - coords[j * 3 + 0];
  float dy = coords[i * 3 + 1] - coords[j * 3 + 1];
  float dz = coords[i * 3 + 2] - coords[j * 3 + 2];
  float norm = sqrtf(dx * dx + dy * dy + dz * dz + 1e-12f);
  float inv = 1.f / (1.f + norm);
  float e[7];
  e[0] = dx * inv; e[1] = dy * inv; e[2] = dz * inv;
  e[3] = log1pf(norm);
  e[4] = 1.f / (1.f + expf(-(norm - 2.f)));
  e[5] = 1.f / (1.f + expf(-(norm - 4.f)));
  e[6] = 1.f / (1.f + expf(-(norm - 6.f)));
  const int mt = i >> 4, l16 = i & 15;
  const int k0 = j >> 5, jo = j & 31;
  const int lane = (jo >> 3) * 16 + l16, jj = jo & 7;
  for (int l = 0; l < 4; ++l)
    for (int h = 0; h < 8; ++h) {
      float s = 0.f;
      for (int k = 0; k < 7; ++k) s += e[k] * W_edge[(l * 7 + k) * 8 + h];
      ewbf[(((((l * 8 + h) * 8 + mt) * 4 + k0) * 64) + lane) * 8 + jj] = f2bf(s);
    }
}

// WvTf/WoTf fragment-major: [l][gt(16)][k0(8)][lane(64)][jj(8)] bf16.
__global__ void k_wt(const float* __restrict__ Wv, const float* __restrict__ Wo,
                     unsigned short* __restrict__ WvTf, unsigned short* __restrict__ WoTf) {
  int idx = blockIdx.x * 256 + threadIdx.x;  // 4*65536
  const int l = idx >> 16, rem = idx & 65535;
  const int jj = rem & 7, lane = (rem >> 3) & 63, k0 = (rem >> 9) & 7, gt = rem >> 12;
  const int g = gt * 16 + (lane & 15);
  const int f = k0 * 32 + (lane >> 4) * 8 + jj;
  const int src = l * 65536 + f * 256 + g;
  WvTf[idx] = f2bf(Wv[src]);
  WoTf[idx] = f2bf(Wo[src]);
}

// nucbT[l][g][i] = nuc_feats[i,:] @ W_nuc[l][:,g]  (fp32, transposed)
__global__ void k_nucbT(const float* __restrict__ nuc_feats, const float* __restrict__ W_nuc,
                        float* __restrict__ nucbT) {
  int b = blockIdx.x;  // l*128 + i
  int l = b >> 7, i = b & 127;
  int g = threadIdx.x;
  __shared__ float row[256];
  row[g] = nuc_feats[i * 256 + g];
  __syncthreads();
  const float* Wn = W_nuc + l * 65536;
  float s = 0.f;
  for (int f = 0; f < 256; ++f) s += row[f] * Wn[f * 256 + g];
  nucbT[(l * 256 + g) * 128 + i] = s;
}

// ---------------- fused main kernel ----------------

__global__ __launch_bounds__(512, 4) void k_main(
    float* __restrict__ feats,                // d_out [1024][128][256] fp32
    const float* __restrict__ W_orb,          // [136][256]
    const unsigned short* __restrict__ WvTf,  // fragment-major (see k_wt)
    const unsigned short* __restrict__ WoTf,  // fragment-major
    const unsigned short* __restrict__ ewbf,  // fragment-major (see k_ew)
    const float* __restrict__ nucbT,          // [4][256][128] fp32
    const int* __restrict__ orb_nuc, const int* __restrict__ orb_t) {
  __shared__ char SB[65536];  // h -> valsT -> msg (reused via barriers)
  __shared__ float red1[8];   // LN1 max-var partials
  __shared__ float red2[8];   // LN2 max-var partials

  const int o = blockIdx.x;
  const int tid = threadIdx.x;
  const int wave = tid >> 6;
  const int lane = tid & 63;
  const int l16 = lane & 15;
  const int kgrp = (lane >> 4) << 3;  // A/B fragment k-offset: 0,8,16,24
  const int rgrp = (lane >> 4) << 2;  // D fragment row group: 0,4,8,12
  const int w16 = wave * 16;          // this wave's 16 rows

  const int nn = orb_nuc[o];
  const int tt = orb_t[o];
  float* fo = feats + (size_t)o * 32768;

  // residual, bf16-packed: frw[2gt]={r0,r1}, frw[2gt+1]={r2,r3} of
  // feats[w16+rgrp+r][gt*16+l16]. Pinned to AGPRs (asm "+a") so the 64/64
  // unified split hosts it outside the arch half.
  unsigned int frw[32];
#pragma unroll
  for (int gt = 0; gt < 16; ++gt) {
    float v[4] = {0.f, 0.f, 0.f, 0.f};
#pragma unroll
    for (int r = 0; r < 4; ++r)
      if (w16 + rgrp + r == nn) v[r] = W_orb[tt * 256 + gt * 16 + l16];
    frw[2 * gt] = packbf(v[0], v[1]);
    frw[2 * gt + 1] = packbf(v[2], v[3]);
  }
#pragma unroll
  for (int i = 0; i < 32; ++i) asm volatile("" : "+a"(frw[i]));

#pragma unroll 1
  for (int l = 0; l < 4; ++l) {
    // ---- LN1 (wave-local): stats from frw, centered h -> private SB rows,
    //      A-fragments hoisted back (in-wave LDS ordering, no barrier) ----
    bf16x8 A[8];
    {
      float s4[4] = {0, 0, 0, 0}, q4[4] = {0, 0, 0, 0};
#pragma unroll
      for (int gt = 0; gt < 16; ++gt) {
        const float v0 = lo16f(frw[2 * gt]), v1 = hi16f(frw[2 * gt]);
        const float v2 = lo16f(frw[2 * gt + 1]), v3 = hi16f(frw[2 * gt + 1]);
        s4[0] += v0; q4[0] += v0 * v0;
        s4[1] += v1; q4[1] += v1 * v1;
        s4[2] += v2; q4[2] += v2 * v2;
        s4[3] += v3; q4[3] += v3 * v3;
      }
#pragma unroll
      for (int of = 1; of < 16; of <<= 1)
#pragma unroll
        for (int r = 0; r < 4; ++r) {
          s4[r] += __shfl_xor(s4[r], of);
          q4[r] += __shfl_xor(q4[r], of);
        }
      float mean[4], maxv = 0.f;
#pragma unroll
      for (int r = 0; r < 4; ++r) {
        mean[r] = s4[r] * (1.f / 256.f);
        const float var = q4[r] * (1.f / 256.f) - mean[r] * mean[r];
        maxv = fmaxf(maxv, var);
      }
      maxv = fmaxf(maxv, __shfl_xor(maxv, 16));
      maxv = fmaxf(maxv, __shfl_xor(maxv, 32));
      if (lane == 0) red1[wave] = maxv;
#pragma unroll
      for (int gt = 0; gt < 16; ++gt) {
        const float v0 = lo16f(frw[2 * gt]), v1 = hi16f(frw[2 * gt]);
        const float v2 = lo16f(frw[2 * gt + 1]), v3 = hi16f(frw[2 * gt + 1]);
        const int cb = (gt * 16 + l16) * 2;
        *(unsigned short*)(SB + swzA(w16 + rgrp + 0, cb)) = f2bf(v0 - mean[0]);
        *(unsigned short*)(SB + swzA(w16 + rgrp + 1, cb)) = f2bf(v1 - mean[1]);
        *(unsigned short*)(SB + swzA(w16 + rgrp + 2, cb)) = f2bf(v2 - mean[2]);
        *(unsigned short*)(SB + swzA(w16 + rgrp + 3, cb)) = f2bf(v3 - mean[3]);
      }
#pragma unroll
      for (int k0 = 0; k0 < 8; ++k0)
        A[k0] = *(const bf16x8*)(SB + swzA(w16 + l16, (k0 * 32 + kgrp) * 2));
    }
    __syncthreads();  // B1: A-frags hoisted + red1 ready; SB reusable

    // ---- GEMM1: valsT[g][n] = rstd*(h @ W_val); b streamed in pairs ----
    {
      float mv = red1[0];
#pragma unroll
      for (int w = 1; w < 8; ++w) mv = fmaxf(mv, red1[w]);
      const float rstd = rsqrtf(mv + 1.f);
      const unsigned short* Wl = WvTf + (l * 65536) + lane * 8;
#pragma unroll
      for (int gt = 0; gt < 16; ++gt) {
        f32x4 acc = {0.f, 0.f, 0.f, 0.f};
        bf16x8 b0, b1;
        b0 = *(const bf16x8*)(Wl + (gt * 8 + 0) * 512);
        b1 = *(const bf16x8*)(Wl + (gt * 8 + 1) * 512);
        acc = __builtin_amdgcn_mfma_f32_16x16x32_bf16(A[0], b0, acc, 0, 0, 0);
        acc = __builtin_amdgcn_mfma_f32_16x16x32_bf16(A[1], b1, acc, 0, 0, 0);
        b0 = *(const bf16x8*)(Wl + (gt * 8 + 2) * 512);
        b1 = *(const bf16x8*)(Wl + (gt * 8 + 3) * 512);
        acc = __builtin_amdgcn_mfma_f32_16x16x32_bf16(A[2], b0, acc, 0, 0, 0);
        acc = __builtin_amdgcn_mfma_f32_16x16x32_bf16(A[3], b1, acc, 0, 0, 0);
        b0 = *(const bf16x8*)(Wl + (gt * 8 + 4) * 512);
        b1 = *(const bf16x8*)(Wl + (gt * 8 + 5) * 512);
        acc = __builtin_amdgcn_mfma_f32_16x16x32_bf16(A[4], b0, acc, 0, 0, 0);
        acc = __builtin_amdgcn_mfma_f32_16x16x32_bf16(A[5], b1, acc, 0, 0, 0);
        b0 = *(const bf16x8*)(Wl + (gt * 8 + 6) * 512);
        b1 = *(const bf16x8*)(Wl + (gt * 8 + 7) * 512);
        acc = __builtin_amdgcn_mfma_f32_16x16x32_bf16(A[6], b0, acc, 0, 0, 0);
        acc = __builtin_amdgcn_mfma_f32_16x16x32_bf16(A[7], b1, acc, 0, 0, 0);
        const int gg = gt * 16 + l16;
        US4 ov{f2bf(acc[0] * rstd), f2bf(acc[1] * rstd), f2bf(acc[2] * rstd),
               f2bf(acc[3] * rstd)};
        *(US4*)(SB + swzV(gg, (w16 + rgrp) * 2)) = ov;
      }
    }
    __syncthreads();  // B2: valsT complete

    // ---- hoist this head's valsT slice (f-rows wave*32..+32, K=128) ----
    bf16x8 VB0[4], VB1[4];
#pragma unroll
    for (int k0 = 0; k0 < 4; ++k0) {
      VB0[k0] = *(const bf16x8*)(SB + swzV(wave * 32 + l16, (k0 * 32 + kgrp) * 2));
      VB1[k0] = *(const bf16x8*)(SB + swzV(wave * 32 + 16 + l16, (k0 * 32 + kgrp) * 2));
    }
    __syncthreads();  // B3: all valsT reads done; SB reusable for msg

    // ---- MSG: msg[i][f] = sum_j ew[w][i][j]*valsT[f][j] + nucbT[f][i] ----
    //      (no in-epilogue stats — LN2 stats moved to the raw-read phase)
    {
      const unsigned short* ewh = ewbf + ((l * 8 + wave) * 16384) + lane * 8;
      const float* nbT = nucbT + l * 32768;
      const int f0 = wave * 32 + l16;
      const int f1 = f0 + 16;
#pragma unroll
      for (int mt = 0; mt < 8; ++mt) {
        const int i0 = mt * 16;
        f32x4 acc0 = {0.f, 0.f, 0.f, 0.f}, acc1 = {0.f, 0.f, 0.f, 0.f};
        {
          bf16x8 a0 = *(const bf16x8*)(ewh + (mt * 4 + 0) * 512);
          bf16x8 a1 = *(const bf16x8*)(ewh + (mt * 4 + 1) * 512);
          acc0 = __builtin_amdgcn_mfma_f32_16x16x32_bf16(a0, VB0[0], acc0, 0, 0, 0);
          acc1 = __builtin_amdgcn_mfma_f32_16x16x32_bf16(a0, VB1[0], acc1, 0, 0, 0);
          acc0 = __builtin_amdgcn_mfma_f32_16x16x32_bf16(a1, VB0[1], acc0, 0, 0, 0);
          acc1 = __builtin_amdgcn_mfma_f32_16x16x32_bf16(a1, VB1[1], acc1, 0, 0, 0);
        }
        {
          bf16x8 a0 = *(const bf16x8*)(ewh + (mt * 4 + 2) * 512);
          bf16x8 a1 = *(const bf16x8*)(ewh + (mt * 4 + 3) * 512);
          acc0 = __builtin_amdgcn_mfma_f32_16x16x32_bf16(a0, VB0[2], acc0, 0, 0, 0);
          acc1 = __builtin_amdgcn_mfma_f32_16x16x32_bf16(a0, VB1[2], acc1, 0, 0, 0);
          acc0 = __builtin_amdgcn_mfma_f32_16x16x32_bf16(a1, VB0[3], acc0, 0, 0, 0);
          acc1 = __builtin_amdgcn_mfma_f32_16x16x32_bf16(a1, VB1[3], acc1, 0, 0, 0);
        }
        const f32x4 nb0 = *(const f32x4*)(nbT + f0 * 128 + i0 + rgrp);
        const f32x4 nb1 = *(const f32x4*)(nbT + f1 * 128 + i0 + rgrp);
#pragma unroll
        for (int r = 0; r < 4; ++r) {
          *(unsigned short*)(SB + swzA(i0 + rgrp + r, f0 * 2)) = f2bf(acc0[r] + nb0[r]);
          *(unsigned short*)(SB + swzA(i0 + rgrp + r, f1 * 2)) = f2bf(acc1[r] + nb1[r]);
        }
      }
    }
    __syncthreads();  // B4: msg complete

    // ---- LN2 stats from raw fragments (row w16+l16, split over 4 kg-lanes) ----
    bf16x8 raw[8];
    float mn;
    {
#pragma unroll
      for (int k0 = 0; k0 < 8; ++k0)
        raw[k0] = *(const bf16x8*)(SB + swzA(w16 + l16, (k0 * 32 + kgrp) * 2));
      float s = 0.f, q = 0.f;
#pragma unroll
      for (int k0 = 0; k0 < 8; ++k0)
#pragma unroll
        for (int j = 0; j < 8; ++j) {
          const float v = (float)raw[k0][j];
          s += v;
          q += v * v;
        }
      s += __shfl_xor(s, 16); s += __shfl_xor(s, 32);
      q += __shfl_xor(q, 16); q += __shfl_xor(q, 32);
      mn = s * (1.f / 256.f);
      float maxv = q * (1.f / 256.f) - mn * mn;
#pragma unroll
      for (int of = 1; of < 16; of <<= 1) maxv = fmaxf(maxv, __shfl_xor(maxv, of));
      if (lane == 0) red2[wave] = maxv;
    }
    __syncthreads();  // B5: red2 ready

    // ---- tanh in place + GEMM2 (b streamed in pairs, acc seeded from frw) ----
    {
      float mv = red2[0];
#pragma unroll
      for (int w = 1; w < 8; ++w) mv = fmaxf(mv, red2[w]);
      const float rstd2 = rsqrtf(mv + 1.f);
#pragma unroll
      for (int k0 = 0; k0 < 8; ++k0) {
        bf16x8 t;
#pragma unroll
        for (int j = 0; j < 8; ++j)
          t[j] = (__bf16)ftanh(((float)raw[k0][j] - mn) * rstd2);
        raw[k0] = t;
      }
      const unsigned short* Wl = WoTf + (l * 65536) + lane * 8;
#pragma unroll
      for (int gt = 0; gt < 16; ++gt) {
        f32x4 acc = {lo16f(frw[2 * gt]), hi16f(frw[2 * gt]),
                     lo16f(frw[2 * gt + 1]), hi16f(frw[2 * gt + 1])};
        bf16x8 b0, b1;
        b0 = *(const bf16x8*)(Wl + (gt * 8 + 0) * 512);
        b1 = *(const bf16x8*)(Wl + (gt * 8 + 1) * 512);
        acc = __builtin_amdgcn_mfma_f32_16x16x32_bf16(raw[0], b0, acc, 0, 0, 0);
        acc = __builtin_amdgcn_mfma_f32_16x16x32_bf16(raw[1], b1, acc, 0, 0, 0);
        b0 = *(const bf16x8*)(Wl + (gt * 8 + 2) * 512);
        b1 = *(const bf16x8*)(Wl + (gt * 8 + 3) * 512);
        acc = __builtin_amdgcn_mfma_f32_16x16x32_bf16(raw[2], b0, acc, 0, 0, 0);
        acc = __builtin_amdgcn_mfma_f32_16x16x32_bf16(raw[3], b1, acc, 0, 0, 0);
        b0 = *(const bf16x8*)(Wl + (gt * 8 + 4) * 512);
        b1 = *(const bf16x8*)(Wl + (gt * 8 + 5) * 512);
        acc = __builtin_amdgcn_mfma_f32_16x16x32_bf16(raw[4], b0, acc, 0, 0, 0);
        acc = __builtin_amdgcn_mfma_f32_16x16x32_bf16(raw[5], b1, acc, 0, 0, 0);
        b0 = *(const bf16x8*)(Wl + (gt * 8 + 6) * 512);
        b1 = *(const bf16x8*)(Wl + (gt * 8 + 7) * 512);
        acc = __builtin_amdgcn_mfma_f32_16x16x32_bf16(raw[6], b0, acc, 0, 0, 0);
        acc = __builtin_amdgcn_mfma_f32_16x16x32_bf16(raw[7], b1, acc, 0, 0, 0);
        frw[2 * gt] = packbf(acc[0], acc[1]);
        frw[2 * gt + 1] = packbf(acc[2], acc[3]);
      }
    }
#pragma unroll
    for (int i = 0; i < 32; ++i) asm volatile("" : "+a"(frw[i]));
    // no end-of-layer barrier: LN2 raw reads (own rows) finished before B5;
    // next-layer LN1 h-writes hit only this wave's own rows.
  }

  // ---- final store from frw (64B segments per l16 group) ----
#pragma unroll
  for (int gt = 0; gt < 16; ++gt) {
    const int base = gt * 16 + l16;
    fo[(w16 + rgrp + 0) * 256 + base] = lo16f(frw[2 * gt]);
    fo[(w16 + rgrp + 1) * 256 + base] = hi16f(frw[2 * gt]);
    fo[(w16 + rgrp + 2) * 256 + base] = lo16f(frw[2 * gt + 1]);
    fo[(w16 + rgrp + 3) * 256 + base] = hi16f(frw[2 * gt + 1]);
  }
}

// ---------------- launcher ----------------

extern "C" void kernel_launch(void* const* d_in, const int* in_sizes, int n_in,
                              void* d_out, int out_size, void* d_ws, size_t ws_size,
                              hipStream_t stream) {
  const float* coords = (const float*)d_in[0];
  const int* charges = (const int*)d_in[1];
  const int* n_up = (const int*)d_in[3];
  const int* n_down = (const int*)d_in[4];
  const float* nuc_feats = (const float*)d_in[5];
  const float* W_orb = (const float*)d_in[7];
  const float* W_edge = (const float*)d_in[8];
  const float* W_val = (const float*)d_in[9];
  const float* W_nuc = (const float*)d_in[10];
  const float* W_out = (const float*)d_in[11];
  float* out = (float*)d_out;

  char* ws = (char*)d_ws;
  int* orb_nuc = (int*)ws;                                        // 4KB
  int* orb_t = (int*)(ws + 4096);                                 // 4KB
  unsigned short* ewbf = (unsigned short*)(ws + 8192);            // 1MB
  unsigned short* WvTf = (unsigned short*)(ws + 8192 + 1048576);  // 512KB
  unsigned short* WoTf = WvTf + 262144;                           // 512KB
  float* nucbT = (float*)(ws + 8192 + 1048576 + 1048576);         // 512KB

  k_orbmap<<<dim3(1), dim3(256), 0, stream>>>(charges, n_up, n_down, orb_nuc, orb_t);
  k_ew<<<dim3(128), dim3(128), 0, stream>>>(coords, W_edge, ewbf);
  k_wt<<<dim3(1024), dim3(256), 0, stream>>>(W_val, W_out, WvTf, WoTf);
  k_nucbT<<<dim3(512), dim3(256), 0, stream>>>(nuc_feats, W_nuc, nucbT);
  k_main<<<dim3(O_TOT), dim3(512), 0, stream>>>(out, W_orb, WvTf, WoTf, ewbf, nucbT,
                                                orb_nuc, orb_t);
}

// Round 15
// 833.297 us; speedup vs baseline: 1.1758x; 1.1758x over previous
//
#include <hip/hip_runtime.h>
#include <hip/hip_bf16.h>

// OrbitalGenerator: 1024 independent [128x256] slices through a 4-layer MPNN.
// One block per orbital, 512 threads (8 waves), (512,2) clean-register regime.
// R15: COLUMN-ownership decomposition. Wave w owns g-cols [w*32, w*32+32):
//  - GEMM1/GEMM2: wave hoists only ITS 16 weight fragments (16 independent
//    global loads vs R10's 128 dependent ones); A-fragments re-read from LDS
//    per m-tile. Weight traffic per block becomes non-redundant (3.6x less).
//  - GEMM1 output rows == the vals slice wave w's head consumes -> vals is an
//    8KB wave-PRIVATE LDS transpose region (no barrier, no 64KB valsT pass).
//  - LN1/LN2 stats are cross-wave: per-wave 32-col partials (16-lane shuffle)
//    -> lnP -> combine phase (threads<128) -> meanL[128] + maxvar red[2].
// 6 barriers/layer. Residual fr[8][2] f32x4 seeds GEMM2 MFMA chains (AGPR).

#define O_TOT 1024

typedef __bf16 bf16x8 __attribute__((ext_vector_type(8)));
typedef float f32x4 __attribute__((ext_vector_type(4)));

static __device__ __forceinline__ unsigned short f2bf(float f) {
  __bf16 b = (__bf16)f;
  unsigned short u;
  __builtin_memcpy(&u, &b, 2);
  return u;
}
static __device__ __forceinline__ float ftanh(float x) {
  float e = __expf(2.f * x);
  return 1.f - 2.f * __builtin_amdgcn_rcpf(e + 1.f);
}

struct alignas(8) US4 { unsigned short a, b, c, d; };

// XOR swizzles with 2 row bits -> 16 distinct 16B slots per 16 consecutive rows.
static __device__ __forceinline__ int swzA(int row, int cb) {  // [128][512B]
  return row * 512 + (cb ^ ((row & 7) << 4) ^ (((row >> 3) & 1) << 5));
}
static __device__ __forceinline__ int swzV(int row, int cb) {  // [32][256B]
  return row * 256 + (cb ^ ((row & 7) << 4) ^ (((row >> 3) & 1) << 5));
}

// ---------------- setup kernels (identical to R10) ----------------

__global__ void k_orbmap(const int* __restrict__ charges, const int* __restrict__ n_up_p,
                         const int* __restrict__ n_down_p, int* __restrict__ orb_nuc,
                         int* __restrict__ orb_t) {
  __shared__ int off[129];
  __shared__ int prec[128];
  int tid = threadIdx.x;
  if (tid == 0) {
    int a = 0;
    for (int n = 0; n < 128; ++n) { off[n] = a; a += charges[n]; }
    off[128] = a;
  }
  if (tid < 128) prec[tid] = charges[tid] * (charges[tid] - 1) / 2;
  __syncthreads();
  int nu = *n_up_p, nd = *n_down_p;
  for (int o = tid; o < O_TOT; o += 256) {
    int e;
    if (o < nu) e = o;
    else if (o < 512) e = o + nd;
    else if (o < 512 + nd) e = o + nu - 512;
    else e = o;
    int nn = -1, tt = 0;
    for (int n = 0; n < 128; ++n) {
      if (e >= off[n] && e < off[n + 1]) { nn = n; tt = prec[n] + (e - off[n]); }
    }
    orb_nuc[o] = nn;
    orb_t[o] = tt;
  }
}

// ewbf fragment-major: [l][h][mt(8)][k0(4)][lane(64)][j(8)] bf16 (1MB total).
__global__ void k_ew(const float* __restrict__ coords, const float* __restrict__ W_edge,
                     unsigned short* __restrict__ ewbf) {
  int i = blockIdx.x, j = threadIdx.x;
  float dx = coords[i * 3 + 0] - coords[j * 3 + 0];
  float dy = coords[i * 3 + 1] - coords[j * 3 + 1];
  float dz = coords[i * 3 + 2] - coords[j * 3 + 2];
  float norm = sqrtf(dx * dx + dy * dy + dz * dz + 1e-12f);
  float inv = 1.f / (1.f + norm);
  float e[7];
  e[0] = dx * inv; e[1] = dy * inv; e[2] = dz * inv;
  e[3] = log1pf(norm);
  e[4] = 1.f / (1.f + expf(-(norm - 2.f)));
  e[5] = 1.f / (1.f + expf(-(norm - 4.f)));
  e[6] = 1.f / (1.f + expf(-(norm - 6.f)));
  const int mt = i >> 4, l16 = i & 15;
  const int k0 = j >> 5, jo = j & 31;
  const int lane = (jo >> 3) * 16 + l16, jj = jo & 7;
  for (int l = 0; l < 4; ++l)
    for (int h = 0; h < 8; ++h) {
      float s = 0.f;
      for (int k = 0; k < 7; ++k) s += e[k] * W_edge[(l * 7 + k) * 8 + h];
      ewbf[(((((l * 8 + h) * 8 + mt) * 4 + k0) * 64) + lane) * 8 + jj] = f2bf(s);
    }
}

// WvTf/WoTf fragment-major: [l][gt(16)][k0(8)][lane(64)][jj(8)] bf16.
__global__ void k_wt(const float* __restrict__ Wv, const float* __restrict__ Wo,
                     unsigned short* __restrict__ WvTf, unsigned short* __restrict__ WoTf) {
  int idx = blockIdx.x * 256 + threadIdx.x;  // 4*65536
  const int l = idx >> 16, rem = idx & 65535;
  const int jj = rem & 7, lane = (rem >> 3) & 63, k0 = (rem >> 9) & 7, gt = rem >> 12;
  const int g = gt * 16 + (lane & 15);
  const int f = k0 * 32 + (lane >> 4) * 8 + jj;
  const int src = l * 65536 + f * 256 + g;
  WvTf[idx] = f2bf(Wv[src]);
  WoTf[idx] = f2bf(Wo[src]);
}

// nucbT[l][g][i] = nuc_feats[i,:] @ W_nuc[l][:,g]  (fp32, transposed)
__global__ void k_nucbT(const float* __restrict__ nuc_feats, const float* __restrict__ W_nuc,
                        float* __restrict__ nucbT) {
  int b = blockIdx.x;  // l*128 + i
  int l = b >> 7, i = b & 127;
  int g = threadIdx.x;
  __shared__ float row[256];
  row[g] = nuc_feats[i * 256 + g];
  __syncthreads();
  const float* Wn = W_nuc + l * 65536;
  float s = 0.f;
  for (int f = 0; f < 256; ++f) s += row[f] * Wn[f * 256 + g];
  nucbT[(l * 256 + g) * 128 + i] = s;
}

// ---------------- fused main kernel ----------------

__global__ __launch_bounds__(512, 2) void k_main(
    float* __restrict__ feats,                // d_out [1024][128][256] fp32
    const float* __restrict__ W_orb,          // [136][256]
    const unsigned short* __restrict__ WvTf,  // fragment-major (see k_wt)
    const unsigned short* __restrict__ WoTf,  // fragment-major
    const unsigned short* __restrict__ ewbf,  // fragment-major (see k_ew)
    const float* __restrict__ nucbT,          // [4][256][128] fp32
    const int* __restrict__ orb_nuc, const int* __restrict__ orb_t) {
  __shared__ char SB[65536];       // h -> msg (shared, barrier-fenced)
  __shared__ char VALS[65536];     // 8 x 8KB wave-private vals transpose regions
  __shared__ float2 lnP[8][128];   // LN partials (shared LN1/LN2)
  __shared__ float meanL[128];     // row means (shared LN1/LN2)
  __shared__ float red[2];         // max-var partials (rows 0-63 / 64-127)

  const int o = blockIdx.x;
  const int tid = threadIdx.x;
  const int wave = tid >> 6;
  const int lane = tid & 63;
  const int l16 = lane & 15;
  const int kgrp = (lane >> 4) << 3;  // A/B fragment k-offset: 0,8,16,24
  const int rgrp = (lane >> 4) << 2;  // D fragment row group: 0,4,8,12
  const int C0 = wave * 32;           // this wave's 32 g-columns (= head cols)

  const int nn = orb_nuc[o];
  const int tt = orb_t[o];
  float* fo = feats + (size_t)o * 32768;
  char* vreg = VALS + wave * 8192;    // wave-private [32][256B] region

  // residual: fr[mt][j][r] = feats[mt*16+rgrp+r][C0 + j*16 + l16]  (64 f32, AGPR)
  f32x4 fr[8][2];
#pragma unroll
  for (int mt = 0; mt < 8; ++mt)
#pragma unroll
    for (int j = 0; j < 2; ++j) {
      f32x4 v = {0.f, 0.f, 0.f, 0.f};
#pragma unroll
      for (int r = 0; r < 4; ++r)
        if (mt * 16 + rgrp + r == nn) v[r] = W_orb[tt * 256 + C0 + j * 16 + l16];
      fr[mt][j] = v;
    }

#pragma unroll 1
  for (int l = 0; l < 4; ++l) {
    // ---- P1: LN1 partials (32-col sums per row) -> lnP[wave] ----
    {
#pragma unroll
      for (int mt = 0; mt < 8; ++mt) {
        float s[4], q[4];
#pragma unroll
        for (int r = 0; r < 4; ++r) {
          const float v0 = fr[mt][0][r], v1 = fr[mt][1][r];
          s[r] = v0 + v1;
          q[r] = v0 * v0 + v1 * v1;
        }
#pragma unroll
        for (int of = 1; of < 16; of <<= 1)
#pragma unroll
          for (int r = 0; r < 4; ++r) {
            s[r] += __shfl_xor(s[r], of);
            q[r] += __shfl_xor(q[r], of);
          }
#pragma unroll
        for (int r = 0; r < 4; ++r)
          if (l16 == (((mt & 3) << 2) | r))
            lnP[wave][mt * 16 + rgrp + r] = float2{s[r], q[r]};
      }
    }
    __syncthreads();  // B1: lnP complete

    // ---- P2: combine -> meanL[128] + red[2] ----
    if (tid < 128) {
      float S = 0.f, Q = 0.f;
#pragma unroll
      for (int w2 = 0; w2 < 8; ++w2) {
        const float2 p = lnP[w2][tid];
        S += p.x; Q += p.y;
      }
      const float mean = S * (1.f / 256.f);
      float var = Q * (1.f / 256.f) - mean * mean;
      meanL[tid] = mean;
#pragma unroll
      for (int of = 1; of < 64; of <<= 1) var = fmaxf(var, __shfl_xor(var, of));
      if (lane == 0) red[wave] = var;
    }
    __syncthreads();  // B2: meanL + red ready
    const float rstd = rsqrtf(fmaxf(red[0], red[1]) + 1.f);

    // ---- P3: h-write (centered, bf16) for this wave's 32 cols, all rows ----
    {
#pragma unroll
      for (int mt = 0; mt < 8; ++mt) {
        const f32x4 m4 = *(const f32x4*)(meanL + mt * 16 + rgrp);
#pragma unroll
        for (int j = 0; j < 2; ++j) {
          const int cb = (C0 + j * 16 + l16) * 2;
#pragma unroll
          for (int r = 0; r < 4; ++r)
            *(unsigned short*)(SB + swzA(mt * 16 + rgrp + r, cb)) =
                f2bf(fr[mt][j][r] - m4[r]);
        }
      }
    }
    __syncthreads();  // B3: h complete

    // ---- P4: GEMM1 — b hoisted (own 2 gt, 16 loads), A from LDS per mt;
    //      output -> wave-private vals region (transpose for MSG B-frags) ----
    {
      const unsigned short* Wl = WvTf + l * 65536 + lane * 8;
      bf16x8 b[16];
#pragma unroll
      for (int j = 0; j < 2; ++j)
#pragma unroll
        for (int k0 = 0; k0 < 8; ++k0)
          b[j * 8 + k0] = *(const bf16x8*)(Wl + (((2 * wave + j) * 8 + k0) * 512));
#pragma unroll
      for (int mt = 0; mt < 8; ++mt) {
        bf16x8 A[8];
#pragma unroll
        for (int k0 = 0; k0 < 8; ++k0)
          A[k0] = *(const bf16x8*)(SB + swzA(mt * 16 + l16, (k0 * 32 + kgrp) * 2));
        f32x4 acc0 = {0.f, 0.f, 0.f, 0.f}, acc1 = {0.f, 0.f, 0.f, 0.f};
#pragma unroll
        for (int k0 = 0; k0 < 8; ++k0) {
          acc0 = __builtin_amdgcn_mfma_f32_16x16x32_bf16(A[k0], b[k0], acc0, 0, 0, 0);
          acc1 = __builtin_amdgcn_mfma_f32_16x16x32_bf16(A[k0], b[8 + k0], acc1, 0, 0, 0);
        }
        const int cb = (mt * 16 + rgrp) * 2;
        US4 o0{f2bf(acc0[0] * rstd), f2bf(acc0[1] * rstd), f2bf(acc0[2] * rstd),
               f2bf(acc0[3] * rstd)};
        US4 o1{f2bf(acc1[0] * rstd), f2bf(acc1[1] * rstd), f2bf(acc1[2] * rstd),
               f2bf(acc1[3] * rstd)};
        *(US4*)(vreg + swzV(l16, cb)) = o0;
        *(US4*)(vreg + swzV(16 + l16, cb)) = o1;
      }
    }
    __syncthreads();  // B4: h reads done (SB reusable for msg) + vals visible

    // ---- P5: MSG — VB from own vals region; a (own head) + nucbT from
    //      global; msg -> SB; LN2 partials -> lnP ----
    {
      bf16x8 VB0[4], VB1[4];
#pragma unroll
      for (int k0 = 0; k0 < 4; ++k0) {
        VB0[k0] = *(const bf16x8*)(vreg + swzV(l16, (k0 * 32 + kgrp) * 2));
        VB1[k0] = *(const bf16x8*)(vreg + swzV(16 + l16, (k0 * 32 + kgrp) * 2));
      }
      const unsigned short* ewh = ewbf + (l * 8 + wave) * 16384 + lane * 8;
      const float* nbT = nucbT + l * 32768;
      const int f0 = C0 + l16;
      const int f1 = f0 + 16;
#pragma unroll
      for (int mt = 0; mt < 8; ++mt) {
        const int i0 = mt * 16;
        bf16x8 a[4];
#pragma unroll
        for (int k0 = 0; k0 < 4; ++k0)
          a[k0] = *(const bf16x8*)(ewh + (mt * 4 + k0) * 512);
        f32x4 acc0 = {0.f, 0.f, 0.f, 0.f}, acc1 = {0.f, 0.f, 0.f, 0.f};
#pragma unroll
        for (int k0 = 0; k0 < 4; ++k0) {
          acc0 = __builtin_amdgcn_mfma_f32_16x16x32_bf16(a[k0], VB0[k0], acc0, 0, 0, 0);
          acc1 = __builtin_amdgcn_mfma_f32_16x16x32_bf16(a[k0], VB1[k0], acc1, 0, 0, 0);
        }
        const f32x4 nb0 = *(const f32x4*)(nbT + f0 * 128 + i0 + rgrp);
        const f32x4 nb1 = *(const f32x4*)(nbT + f1 * 128 + i0 + rgrp);
        float sp[4], qp[4];
#pragma unroll
        for (int r = 0; r < 4; ++r) {
          const float v0 = acc0[r] + nb0[r];
          const float v1 = acc1[r] + nb1[r];
          *(unsigned short*)(SB + swzA(i0 + rgrp + r, f0 * 2)) = f2bf(v0);
          *(unsigned short*)(SB + swzA(i0 + rgrp + r, f1 * 2)) = f2bf(v1);
          sp[r] = v0 + v1;
          qp[r] = v0 * v0 + v1 * v1;
        }
#pragma unroll
        for (int of = 1; of < 16; of <<= 1)
#pragma unroll
          for (int r = 0; r < 4; ++r) {
            sp[r] += __shfl_xor(sp[r], of);
            qp[r] += __shfl_xor(qp[r], of);
          }
#pragma unroll
        for (int r = 0; r < 4; ++r)
          if (l16 == (((mt & 3) << 2) | r))
            lnP[wave][i0 + rgrp + r] = float2{sp[r], qp[r]};
      }
    }
    __syncthreads();  // B5: msg + lnP(LN2) complete

    // ---- P6: LN2 combine -> meanL + red ----
    if (tid < 128) {
      float S = 0.f, Q = 0.f;
#pragma unroll
      for (int w2 = 0; w2 < 8; ++w2) {
        const float2 p = lnP[w2][tid];
        S += p.x; Q += p.y;
      }
      const float mean = S * (1.f / 256.f);
      float var = Q * (1.f / 256.f) - mean * mean;
      meanL[tid] = mean;
#pragma unroll
      for (int of = 1; of < 64; of <<= 1) var = fmaxf(var, __shfl_xor(var, of));
      if (lane == 0) red[wave] = var;
    }
    __syncthreads();  // B6: meanL(LN2) + red ready
    const float rstd2 = rsqrtf(fmaxf(red[0], red[1]) + 1.f);

    // ---- P7: GEMM2 — b2 hoisted (own 2 gt), A2 = tanh(msg row) per mt,
    //      acc seeded from fr (residual add free, AGPR-resident) ----
    {
      const unsigned short* Wl2 = WoTf + l * 65536 + lane * 8;
      bf16x8 b2[16];
#pragma unroll
      for (int j = 0; j < 2; ++j)
#pragma unroll
        for (int k0 = 0; k0 < 8; ++k0)
          b2[j * 8 + k0] = *(const bf16x8*)(Wl2 + (((2 * wave + j) * 8 + k0) * 512));
#pragma unroll
      for (int mt = 0; mt < 8; ++mt) {
        const float mrow = meanL[mt * 16 + l16];
        bf16x8 A2[8];
#pragma unroll
        for (int k0 = 0; k0 < 8; ++k0) {
          bf16x8 raw = *(const bf16x8*)(SB + swzA(mt * 16 + l16, (k0 * 32 + kgrp) * 2));
          bf16x8 t;
#pragma unroll
          for (int jj = 0; jj < 8; ++jj)
            t[jj] = (__bf16)ftanh(((float)raw[jj] - mrow) * rstd2);
          A2[k0] = t;
        }
        f32x4 acc0 = fr[mt][0];
        f32x4 acc1 = fr[mt][1];
#pragma unroll
        for (int k0 = 0; k0 < 8; ++k0) {
          acc0 = __builtin_amdgcn_mfma_f32_16x16x32_bf16(A2[k0], b2[k0], acc0, 0, 0, 0);
          acc1 = __builtin_amdgcn_mfma_f32_16x16x32_bf16(A2[k0], b2[8 + k0], acc1, 0, 0, 0);
        }
        fr[mt][0] = acc0;
        fr[mt][1] = acc1;
      }
    }
    // no end-of-layer barrier: next P1 is register-only; B1/B2 fence lnP and
    // SB reuse against all waves' P7 reads (barrier semantics, see analysis).
  }

  // ---- final store: fr -> global (16 consecutive lanes = 64B segments) ----
#pragma unroll
  for (int mt = 0; mt < 8; ++mt)
#pragma unroll
    for (int j = 0; j < 2; ++j)
#pragma unroll
      for (int r = 0; r < 4; ++r)
        fo[(mt * 16 + rgrp + r) * 256 + C0 + j * 16 + l16] = fr[mt][j][r];
}

// ---------------- launcher ----------------

extern "C" void kernel_launch(void* const* d_in, const int* in_sizes, int n_in,
                              void* d_out, int out_size, void* d_ws, size_t ws_size,
                              hipStream_t stream) {
  const float* coords = (const float*)d_in[0];
  const int* charges = (const int*)d_in[1];
  const int* n_up = (const int*)d_in[3];
  const int* n_down = (const int*)d_in[4];
  const float* nuc_feats = (const float*)d_in[5];
  const float* W_orb = (const float*)d_in[7];
  const float* W_edge = (const float*)d_in[8];
  const float* W_val = (const float*)d_in[9];
  const float* W_nuc = (const float*)d_in[10];
  const float* W_out = (const float*)d_in[11];
  float* out = (float*)d_out;

  char* ws = (char*)d_ws;
  int* orb_nuc = (int*)ws;                                        // 4KB
  int* orb_t = (int*)(ws + 4096);                                 // 4KB
  unsigned short* ewbf = (unsigned short*)(ws + 8192);            // 1MB
  unsigned short* WvTf = (unsigned short*)(ws + 8192 + 1048576);  // 512KB
  unsigned short* WoTf = WvTf + 262144;                           // 512KB
  float* nucbT = (float*)(ws + 8192 + 1048576 + 1048576);         // 512KB

  k_orbmap<<<dim3(1), dim3(256), 0, stream>>>(charges, n_up, n_down, orb_nuc, orb_t);
  k_ew<<<dim3(128), dim3(128), 0, stream>>>(coords, W_edge, ewbf);
  k_wt<<<dim3(1024), dim3(256), 0, stream>>>(W_val, W_out, WvTf, WoTf);
  k_nucbT<<<dim3(512), dim3(256), 0, stream>>>(nuc_feats, W_nuc, nucbT);
  k_main<<<dim3(O_TOT), dim3(512), 0, stream>>>(out, W_orb, WvTf, WoTf, ewbf, nucbT,
                                                orb_nuc, orb_t);
}

// Round 16
// 790.526 us; speedup vs baseline: 1.2394x; 1.0541x over previous
//
#include <hip/hip_runtime.h>
#include <hip/hip_bf16.h>

// OrbitalGenerator: 1024 independent [128x256] slices through a 4-layer MPNN.
// One block per orbital, 512 threads (8 waves), wave w owns rows w*16..w*16+16.
// R16 = R10 (651us best) + latency-hiding only:
//  1) ping-pong register prefetch of weight fragments (GEMM1/GEMM2 b, MSG a):
//     next tile's loads issue before current tile's MFMAs (T14 issue-early).
//  2) GEMM2's first b-batch issues before the LN2 combine + tanh build.
//  3) valsT in its own 64KB VBUF -> B3 barrier dropped (3 barriers/layer).
// Register regime: (512,2), fr[16] f32x4 in AGPR (R10-proven, no spill).

#define O_TOT 1024

typedef __bf16 bf16x8 __attribute__((ext_vector_type(8)));
typedef float f32x4 __attribute__((ext_vector_type(4)));

static __device__ __forceinline__ unsigned short f2bf(float f) {
  __bf16 b = (__bf16)f;
  unsigned short u;
  __builtin_memcpy(&u, &b, 2);
  return u;
}
static __device__ __forceinline__ float ftanh(float x) {
  float e = __expf(2.f * x);
  return 1.f - 2.f * __builtin_amdgcn_rcpf(e + 1.f);
}

struct alignas(8) US4 { unsigned short a, b, c, d; };

// XOR swizzles with 2 row bits -> 16 distinct 16B slots per 16 consecutive rows.
static __device__ __forceinline__ int swzA(int row, int cb) {  // [128][512B]
  return row * 512 + (cb ^ ((row & 7) << 4) ^ (((row >> 3) & 1) << 5));
}
static __device__ __forceinline__ int swzV(int row, int cb) {  // [256][256B]
  return row * 256 + (cb ^ ((row & 7) << 4) ^ (((row >> 3) & 1) << 5));
}

// ---------------- setup kernels (identical to R10) ----------------

__global__ void k_orbmap(const int* __restrict__ charges, const int* __restrict__ n_up_p,
                         const int* __restrict__ n_down_p, int* __restrict__ orb_nuc,
                         int* __restrict__ orb_t) {
  __shared__ int off[129];
  __shared__ int prec[128];
  int tid = threadIdx.x;
  if (tid == 0) {
    int a = 0;
    for (int n = 0; n < 128; ++n) { off[n] = a; a += charges[n]; }
    off[128] = a;
  }
  if (tid < 128) prec[tid] = charges[tid] * (charges[tid] - 1) / 2;
  __syncthreads();
  int nu = *n_up_p, nd = *n_down_p;
  for (int o = tid; o < O_TOT; o += 256) {
    int e;
    if (o < nu) e = o;
    else if (o < 512) e = o + nd;
    else if (o < 512 + nd) e = o + nu - 512;
    else e = o;
    int nn = -1, tt = 0;
    for (int n = 0; n < 128; ++n) {
      if (e >= off[n] && e < off[n + 1]) { nn = n; tt = prec[n] + (e - off[n]); }
    }
    orb_nuc[o] = nn;
    orb_t[o] = tt;
  }
}

// ewbf fragment-major: [l][h][mt(8)][k0(4)][lane(64)][j(8)] bf16 (1MB total).
__global__ void k_ew(const float* __restrict__ coords, const float* __restrict__ W_edge,
                     unsigned short* __restrict__ ewbf) {
  int i = blockIdx.x, j = threadIdx.x;
  float dx = coords[i * 3 + 0] - coords[j * 3 + 0];
  float dy = coords[i * 3 + 1] - coords[j * 3 + 1];
  float dz = coords[i * 3 + 2] - coords[j * 3 + 2];
  float norm = sqrtf(dx * dx + dy * dy + dz * dz + 1e-12f);
  float inv = 1.f / (1.f + norm);
  float e[7];
  e[0] = dx * inv; e[1] = dy * inv; e[2] = dz * inv;
  e[3] = log1pf(norm);
  e[4] = 1.f / (1.f + expf(-(norm - 2.f)));
  e[5] = 1.f / (1.f + expf(-(norm - 4.f)));
  e[6] = 1.f / (1.f + expf(-(norm - 6.f)));
  const int mt = i >> 4, l16 = i & 15;
  const int k0 = j >> 5, jo = j & 31;
  const int lane = (jo >> 3) * 16 + l16, jj = jo & 7;
  for (int l = 0; l < 4; ++l)
    for (int h = 0; h < 8; ++h) {
      float s = 0.f;
      for (int k = 0; k < 7; ++k) s += e[k] * W_edge[(l * 7 + k) * 8 + h];
      ewbf[(((((l * 8 + h) * 8 + mt) * 4 + k0) * 64) + lane) * 8 + jj] = f2bf(s);
    }
}

// WvTf/WoTf fragment-major: [l][gt(16)][k0(8)][lane(64)][jj(8)] bf16.
__global__ void k_wt(const float* __restrict__ Wv, const float* __restrict__ Wo,
                     unsigned short* __restrict__ WvTf, unsigned short* __restrict__ WoTf) {
  int idx = blockIdx.x * 256 + threadIdx.x;  // 4*65536
  const int l = idx >> 16, rem = idx & 65535;
  const int jj = rem & 7, lane = (rem >> 3) & 63, k0 = (rem >> 9) & 7, gt = rem >> 12;
  const int g = gt * 16 + (lane & 15);
  const int f = k0 * 32 + (lane >> 4) * 8 + jj;
  const int src = l * 65536 + f * 256 + g;
  WvTf[idx] = f2bf(Wv[src]);
  WoTf[idx] = f2bf(Wo[src]);
}

// nucbT[l][g][i] = nuc_feats[i,:] @ W_nuc[l][:,g]  (fp32, transposed)
__global__ void k_nucbT(const float* __restrict__ nuc_feats, const float* __restrict__ W_nuc,
                        float* __restrict__ nucbT) {
  int b = blockIdx.x;  // l*128 + i
  int l = b >> 7, i = b & 127;
  int g = threadIdx.x;
  __shared__ float row[256];
  row[g] = nuc_feats[i * 256 + g];
  __syncthreads();
  const float* Wn = W_nuc + l * 65536;
  float s = 0.f;
  for (int f = 0; f < 256; ++f) s += row[f] * Wn[f * 256 + g];
  nucbT[(l * 256 + g) * 128 + i] = s;
}

// ---------------- fused main kernel ----------------

__global__ __launch_bounds__(512, 2) void k_main(
    float* __restrict__ feats,                // d_out [1024][128][256] fp32
    const float* __restrict__ W_orb,          // [136][256]
    const unsigned short* __restrict__ WvTf,  // fragment-major (see k_wt)
    const unsigned short* __restrict__ WoTf,  // fragment-major
    const unsigned short* __restrict__ ewbf,  // fragment-major (see k_ew)
    const float* __restrict__ nucbT,          // [4][256][128] fp32
    const int* __restrict__ orb_nuc, const int* __restrict__ orb_t) {
  __shared__ char SB[65536];       // h -> msg
  __shared__ char VBUF[65536];     // valsT (separate buffer: B3 dropped)
  __shared__ float2 ln2s[8][128];  // LN2 per-head partials [head][row]{s,ss}
  __shared__ float red[8];

  const int o = blockIdx.x;
  const int tid = threadIdx.x;
  const int wave = tid >> 6;
  const int lane = tid & 63;
  const int l16 = lane & 15;
  const int kgrp = (lane >> 4) << 3;  // A/B fragment k-offset: 0,8,16,24
  const int rgrp = (lane >> 4) << 2;  // D fragment row group: 0,4,8,12
  const int w16 = wave * 16;          // this wave's 16 rows

  const int nn = orb_nuc[o];
  const int tt = orb_t[o];
  float* fo = feats + (size_t)o * 32768;

  // feats residual: fr[gt][r] = feats[w16+rgrp+r][gt*16+l16]  (64 f32, AGPR)
  f32x4 fr[16];
#pragma unroll
  for (int gt = 0; gt < 16; ++gt) {
    f32x4 v = {0.f, 0.f, 0.f, 0.f};
#pragma unroll
    for (int r = 0; r < 4; ++r)
      if (w16 + rgrp + r == nn) v[r] = W_orb[tt * 256 + gt * 16 + l16];
    fr[gt] = v;
  }

#pragma unroll 1
  for (int l = 0; l < 4; ++l) {
    // ---- LN1 (wave-local): stats from fr, centered h -> private SB rows,
    //      A-fragments hoisted back (in-wave LDS ordering, no barrier) ----
    bf16x8 A[8];
    {
      float s[4] = {0, 0, 0, 0}, q[4] = {0, 0, 0, 0};
#pragma unroll
      for (int gt = 0; gt < 16; ++gt)
#pragma unroll
        for (int r = 0; r < 4; ++r) {
          float v = fr[gt][r];
          s[r] += v; q[r] += v * v;
        }
#pragma unroll
      for (int of = 1; of < 16; of <<= 1)
#pragma unroll
        for (int r = 0; r < 4; ++r) {
          s[r] += __shfl_xor(s[r], of);
          q[r] += __shfl_xor(q[r], of);
        }
      float mean[4], maxv = 0.f;
#pragma unroll
      for (int r = 0; r < 4; ++r) {
        mean[r] = s[r] * (1.f / 256.f);
        const float var = q[r] * (1.f / 256.f) - mean[r] * mean[r];
        maxv = fmaxf(maxv, var);
      }
      maxv = fmaxf(maxv, __shfl_xor(maxv, 16));
      maxv = fmaxf(maxv, __shfl_xor(maxv, 32));
      if (lane == 0) red[wave] = maxv;
#pragma unroll
      for (int gt = 0; gt < 16; ++gt)
#pragma unroll
        for (int r = 0; r < 4; ++r)
          *(unsigned short*)(SB + swzA(w16 + rgrp + r, (gt * 16 + l16) * 2)) =
              f2bf(fr[gt][r] - mean[r]);
#pragma unroll
      for (int k0 = 0; k0 < 8; ++k0)
        A[k0] = *(const bf16x8*)(SB + swzA(w16 + l16, (k0 * 32 + kgrp) * 2));
    }
    __syncthreads();  // B1: all A-frags hoisted + red ready

    // ---- GEMM1: valsT[g][n] = rstd*(h @ W_val) -> VBUF; b ping-pong ----
    {
      const unsigned short* Wl = WvTf + l * 65536 + lane * 8;
      bf16x8 bA[8], bB[8];
#pragma unroll
      for (int k0 = 0; k0 < 8; ++k0)
        bA[k0] = *(const bf16x8*)(Wl + k0 * 512);  // gt=0 batch issues first
      float mv = red[0];
#pragma unroll
      for (int w = 1; w < 8; ++w) mv = fmaxf(mv, red[w]);
      const float rstd = rsqrtf(mv + 1.f);
#pragma unroll
      for (int gp = 0; gp < 8; ++gp) {
#pragma unroll
        for (int k0 = 0; k0 < 8; ++k0)
          bB[k0] = *(const bf16x8*)(Wl + ((2 * gp + 1) * 8 + k0) * 512);
        {
          f32x4 acc = {0.f, 0.f, 0.f, 0.f};
#pragma unroll
          for (int k0 = 0; k0 < 8; ++k0)
            acc = __builtin_amdgcn_mfma_f32_16x16x32_bf16(A[k0], bA[k0], acc, 0, 0, 0);
          const int gg = (2 * gp) * 16 + l16;
          US4 ov{f2bf(acc[0] * rstd), f2bf(acc[1] * rstd), f2bf(acc[2] * rstd),
                 f2bf(acc[3] * rstd)};
          *(US4*)(VBUF + swzV(gg, (w16 + rgrp) * 2)) = ov;
        }
        if (gp < 7) {
#pragma unroll
          for (int k0 = 0; k0 < 8; ++k0)
            bA[k0] = *(const bf16x8*)(Wl + ((2 * gp + 2) * 8 + k0) * 512);
        }
        {
          f32x4 acc = {0.f, 0.f, 0.f, 0.f};
#pragma unroll
          for (int k0 = 0; k0 < 8; ++k0)
            acc = __builtin_amdgcn_mfma_f32_16x16x32_bf16(A[k0], bB[k0], acc, 0, 0, 0);
          const int gg = (2 * gp + 1) * 16 + l16;
          US4 ov{f2bf(acc[0] * rstd), f2bf(acc[1] * rstd), f2bf(acc[2] * rstd),
                 f2bf(acc[3] * rstd)};
          *(US4*)(VBUF + swzV(gg, (w16 + rgrp) * 2)) = ov;
        }
      }
    }
    __syncthreads();  // B2: valsT complete

    // ---- hoist this head's valsT slice (f-rows wave*32..+32, K=128) ----
    bf16x8 VB0[4], VB1[4];
#pragma unroll
    for (int k0 = 0; k0 < 4; ++k0) {
      VB0[k0] = *(const bf16x8*)(VBUF + swzV(wave * 32 + l16, (k0 * 32 + kgrp) * 2));
      VB1[k0] = *(const bf16x8*)(VBUF + swzV(wave * 32 + 16 + l16, (k0 * 32 + kgrp) * 2));
    }
    // no barrier (was B3): MSG writes SB, not VBUF; next-layer VBUF write is
    // fenced by this layer's B4 + next layer's B1+B2.

    // ---- MSG: msg[i][f] = sum_j ew[w][i][j]*valsT[f][j] + nucbT[f][i] ----
    //      a ping-pong prefetch; in-epilogue LN2 stats -> ln2s ----
    {
      const unsigned short* ewh = ewbf + (l * 8 + wave) * 16384 + lane * 8;
      const float* nbT = nucbT + l * 32768;
      const int f0 = wave * 32 + l16;
      const int f1 = f0 + 16;

      auto body = [&](int mt, const bf16x8* a) {
        const int i0 = mt * 16;
        f32x4 acc0 = {0.f, 0.f, 0.f, 0.f}, acc1 = {0.f, 0.f, 0.f, 0.f};
#pragma unroll
        for (int k0 = 0; k0 < 4; ++k0) {
          acc0 = __builtin_amdgcn_mfma_f32_16x16x32_bf16(a[k0], VB0[k0], acc0, 0, 0, 0);
          acc1 = __builtin_amdgcn_mfma_f32_16x16x32_bf16(a[k0], VB1[k0], acc1, 0, 0, 0);
        }
        const f32x4 nb0 = *(const f32x4*)(nbT + f0 * 128 + i0 + rgrp);
        const f32x4 nb1 = *(const f32x4*)(nbT + f1 * 128 + i0 + rgrp);
        float sp[4], qp[4];
#pragma unroll
        for (int r = 0; r < 4; ++r) {
          const float v0 = acc0[r] + nb0[r];
          const float v1 = acc1[r] + nb1[r];
          *(unsigned short*)(SB + swzA(i0 + rgrp + r, f0 * 2)) = f2bf(v0);
          *(unsigned short*)(SB + swzA(i0 + rgrp + r, f1 * 2)) = f2bf(v1);
          sp[r] = v0 + v1;
          qp[r] = v0 * v0 + v1 * v1;
        }
#pragma unroll
        for (int of = 1; of < 16; of <<= 1)
#pragma unroll
          for (int r = 0; r < 4; ++r) {
            sp[r] += __shfl_xor(sp[r], of);
            qp[r] += __shfl_xor(qp[r], of);
          }
        if (l16 == 0) {
#pragma unroll
          for (int r = 0; r < 4; ++r)
            ln2s[wave][i0 + rgrp + r] = float2{sp[r], qp[r]};
        }
      };

      bf16x8 aA[4], aB[4];
#pragma unroll
      for (int k0 = 0; k0 < 4; ++k0)
        aA[k0] = *(const bf16x8*)(ewh + k0 * 512);
#pragma unroll
      for (int mp = 0; mp < 4; ++mp) {
#pragma unroll
        for (int k0 = 0; k0 < 4; ++k0)
          aB[k0] = *(const bf16x8*)(ewh + ((2 * mp + 1) * 4 + k0) * 512);
        body(2 * mp, aA);
        if (mp < 3) {
#pragma unroll
          for (int k0 = 0; k0 < 4; ++k0)
            aA[k0] = *(const bf16x8*)(ewh + ((2 * mp + 2) * 4 + k0) * 512);
        }
        body(2 * mp + 1, aB);
      }
    }
    __syncthreads();  // B4: msg + ln2s ready

    // ---- GEMM2: first b-batch issues BEFORE LN2 combine + tanh build ----
    {
      const unsigned short* Wl = WoTf + l * 65536 + lane * 8;
      bf16x8 bA[8], bB[8];
#pragma unroll
      for (int k0 = 0; k0 < 8; ++k0)
        bA[k0] = *(const bf16x8*)(Wl + k0 * 512);  // overlap with VALU below

      float s0 = 0.f, q0 = 0.f, s1v = 0.f, q1v = 0.f;
#pragma unroll
      for (int h = 0; h < 8; ++h) {
        const float2 p0 = ln2s[h][lane];
        const float2 p1 = ln2s[h][lane + 64];
        s0 += p0.x; q0 += p0.y;
        s1v += p1.x; q1v += p1.y;
      }
      const float mean_a = s0 * (1.f / 256.f);
      const float mean_b = s1v * (1.f / 256.f);
      float v0 = q0 * (1.f / 256.f) - mean_a * mean_a;
      float v1 = q1v * (1.f / 256.f) - mean_b * mean_b;
      float mv = fmaxf(v0, v1);
#pragma unroll
      for (int of = 1; of < 64; of <<= 1) mv = fmaxf(mv, __shfl_xor(mv, of));
      const float rstd2 = rsqrtf(mv + 1.f);
      const float meansel = (wave >= 4) ? mean_b : mean_a;
      const float mn = __shfl(meansel, ((wave & 3) << 4) + l16);  // mean of row w16+l16

      bf16x8 A2[8];
#pragma unroll
      for (int k0 = 0; k0 < 8; ++k0) {
        bf16x8 raw = *(const bf16x8*)(SB + swzA(w16 + l16, (k0 * 32 + kgrp) * 2));
        bf16x8 t;
#pragma unroll
        for (int j = 0; j < 8; ++j)
          t[j] = (__bf16)ftanh(((float)raw[j] - mn) * rstd2);
        A2[k0] = t;
      }

#pragma unroll
      for (int gp = 0; gp < 8; ++gp) {
#pragma unroll
        for (int k0 = 0; k0 < 8; ++k0)
          bB[k0] = *(const bf16x8*)(Wl + ((2 * gp + 1) * 8 + k0) * 512);
        {
          f32x4 acc = fr[2 * gp];
#pragma unroll
          for (int k0 = 0; k0 < 8; ++k0)
            acc = __builtin_amdgcn_mfma_f32_16x16x32_bf16(A2[k0], bA[k0], acc, 0, 0, 0);
          fr[2 * gp] = acc;
        }
        if (gp < 7) {
#pragma unroll
          for (int k0 = 0; k0 < 8; ++k0)
            bA[k0] = *(const bf16x8*)(Wl + ((2 * gp + 2) * 8 + k0) * 512);
        }
        {
          f32x4 acc = fr[2 * gp + 1];
#pragma unroll
          for (int k0 = 0; k0 < 8; ++k0)
            acc = __builtin_amdgcn_mfma_f32_16x16x32_bf16(A2[k0], bB[k0], acc, 0, 0, 0);
          fr[2 * gp + 1] = acc;
        }
      }
    }
    // no end-of-layer barrier: GEMM2 reads only this wave's private msg row;
    // next-layer LN1 writes only this wave's private rows (in-wave ordering).
  }

  // ---- final store: direct from fr (64B segments per l16 group) ----
#pragma unroll
  for (int gt = 0; gt < 16; ++gt)
#pragma unroll
    for (int r = 0; r < 4; ++r)
      fo[(w16 + rgrp + r) * 256 + gt * 16 + l16] = fr[gt][r];
}

// ---------------- launcher ----------------

extern "C" void kernel_launch(void* const* d_in, const int* in_sizes, int n_in,
                              void* d_out, int out_size, void* d_ws, size_t ws_size,
                              hipStream_t stream) {
  const float* coords = (const float*)d_in[0];
  const int* charges = (const int*)d_in[1];
  const int* n_up = (const int*)d_in[3];
  const int* n_down = (const int*)d_in[4];
  const float* nuc_feats = (const float*)d_in[5];
  const float* W_orb = (const float*)d_in[7];
  const float* W_edge = (const float*)d_in[8];
  const float* W_val = (const float*)d_in[9];
  const float* W_nuc = (const float*)d_in[10];
  const float* W_out = (const float*)d_in[11];
  float* out = (float*)d_out;

  char* ws = (char*)d_ws;
  int* orb_nuc = (int*)ws;                                        // 4KB
  int* orb_t = (int*)(ws + 4096);                                 // 4KB
  unsigned short* ewbf = (unsigned short*)(ws + 8192);            // 1MB
  unsigned short* WvTf = (unsigned short*)(ws + 8192 + 1048576);  // 512KB
  unsigned short* WoTf = WvTf + 262144;                           // 512KB
  float* nucbT = (float*)(ws + 8192 + 1048576 + 1048576);         // 512KB

  k_orbmap<<<dim3(1), dim3(256), 0, stream>>>(charges, n_up, n_down, orb_nuc, orb_t);
  k_ew<<<dim3(128), dim3(128), 0, stream>>>(coords, W_edge, ewbf);
  k_wt<<<dim3(1024), dim3(256), 0, stream>>>(W_val, W_out, WvTf, WoTf);
  k_nucbT<<<dim3(512), dim3(256), 0, stream>>>(nuc_feats, W_nuc, nucbT);
  k_main<<<dim3(O_TOT), dim3(512), 0, stream>>>(out, W_orb, WvTf, WoTf, ewbf, nucbT,
                                                orb_nuc, orb_t);
}